// Round 1
// baseline (3735.376 us; speedup 1.0000x reference)
//
#include <hip/hip_runtime.h>

// Problem constants (SpatialEncoding_46943992545790)
#define T_STEPS 4
#define NN 50000
#define EE 800000
#define DD 256

// ---------------------------------------------------------------- init
__global__ __launch_bounds__(256) void init_deg_cnt(float* __restrict__ deg,
                                                    int* __restrict__ cnt, int n) {
    int i = blockIdx.x * 256 + threadIdx.x;
    if (i < n) { deg[i] = 1.0f; cnt[i] = 0; }   // self-loop weight 1
}

// ------------------------------------------------- edge pass: deg + counts
__global__ __launch_bounds__(256) void edge_deg_cnt(const int* __restrict__ col,
                                                    const float* __restrict__ w,
                                                    float* __restrict__ deg,
                                                    int* __restrict__ cnt, int e) {
    int i = blockIdx.x * 256 + threadIdx.x;
    if (i < e) {
        int c = col[i];
        atomicAdd(&deg[c], w[i]);
        atomicAdd(&cnt[c], 1);
    }
}

// ---------------------------------------------------------------- dinv
__global__ __launch_bounds__(256) void compute_dinv(const float* __restrict__ deg,
                                                    float* __restrict__ dinv, int n) {
    int i = blockIdx.x * 256 + threadIdx.x;
    if (i < n) {
        float d = deg[i];
        dinv[i] = d > 0.0f ? rsqrtf(d) : 0.0f;
    }
}

// ------------------------------------- single-block exclusive scan of cnt
__global__ __launch_bounds__(1024) void scan_cnt(const int* __restrict__ cnt,
                                                 int* __restrict__ colptr,
                                                 int* __restrict__ next, int n) {
    __shared__ int sm[1024];
    int base = 0;
    for (int start = 0; start < n; start += 1024) {
        int i = start + (int)threadIdx.x;
        int v = (i < n) ? cnt[i] : 0;
        sm[threadIdx.x] = v;
        __syncthreads();
        for (int offd = 1; offd < 1024; offd <<= 1) {
            int t = (threadIdx.x >= (unsigned)offd) ? sm[threadIdx.x - offd] : 0;
            __syncthreads();
            sm[threadIdx.x] += t;
            __syncthreads();
        }
        int excl = sm[threadIdx.x] - v + base;
        if (i < n) { colptr[i] = excl; next[i] = excl; }
        base += sm[1023];
        __syncthreads();
    }
    if (threadIdx.x == 0) colptr[n] = base;
}

// --------------------------------------------- fill CSR (sorted by col)
__global__ __launch_bounds__(256) void fill_csr(const int* __restrict__ row,
                                                const int* __restrict__ col,
                                                const float* __restrict__ w,
                                                const float* __restrict__ dinv,
                                                int* __restrict__ next,
                                                int* __restrict__ srow,
                                                float* __restrict__ snorm, int e) {
    int i = blockIdx.x * 256 + threadIdx.x;
    if (i < e) {
        int r = row[i], c = col[i];
        int p = atomicAdd(&next[c], 1);
        srow[p] = r;
        snorm[p] = dinv[r] * w[i] * dinv[c];
    }
}

// ---------------------------------------------------- embedding gather
__global__ __launch_bounds__(256) void embed_kernel(const int* __restrict__ ids,
                                                    const float* __restrict__ emb,
                                                    float* __restrict__ x, int n) {
    int t = blockIdx.x * 256 + threadIdx.x;
    if (t < n * 64) {                   // 64 float4 per row (D=256)
        int node = t >> 6;
        int j = t & 63;
        ((float4*)x)[(size_t)node * 64 + j] =
            ((const float4*)emb)[(size_t)ids[node] * 64 + j];
    }
}

// ------------------------------------------------------- fp32 SGEMM
// C[M,256] = A[M,256] @ B[256,256], row-major. BM=64, BN=64, BK=16.
// 256 threads, each computes 4x4 microtile.
__global__ __launch_bounds__(256) void sgemm_kernel(const float* __restrict__ A,
                                                    const float* __restrict__ B,
                                                    float* __restrict__ C, int M) {
    __shared__ __align__(16) float As[16][68];   // [k][m], pad 68 -> 2-way max (free)
    __shared__ __align__(16) float Bs[16][64];   // [k][n]

    int tid = threadIdx.x;
    int row0 = blockIdx.y * 64;
    int col0 = blockIdx.x * 64;
    int ty = tid >> 4, tx = tid & 15;

    // A-stage mapping: m = tid/4 (0..63), k = (tid%4)*4 (float4)
    int am = tid >> 2, ak = (tid & 3) << 2;
    bool arow_ok = (row0 + am) < M;
    const float* Aptr = A + (size_t)(row0 + am) * 256 + ak;
    // B-stage mapping: k = tid/16 (0..15), n = (tid%16)*4 (float4)
    int bk = tid >> 4, bn = (tid & 15) << 2;

    float acc[4][4];
#pragma unroll
    for (int i = 0; i < 4; ++i)
#pragma unroll
        for (int j = 0; j < 4; ++j) acc[i][j] = 0.0f;

    for (int k0 = 0; k0 < 256; k0 += 16) {
        float4 av = arow_ok ? *(const float4*)(Aptr + k0)
                            : make_float4(0.f, 0.f, 0.f, 0.f);
        float4 bv = *(const float4*)(B + (size_t)(k0 + bk) * 256 + col0 + bn);
        __syncthreads();
        As[ak + 0][am] = av.x;
        As[ak + 1][am] = av.y;
        As[ak + 2][am] = av.z;
        As[ak + 3][am] = av.w;
        *(float4*)&Bs[bk][bn] = bv;
        __syncthreads();
#pragma unroll
        for (int k = 0; k < 16; ++k) {
            float4 a4 = *(const float4*)&As[k][ty << 2];
            float4 b4 = *(const float4*)&Bs[k][tx << 2];
            acc[0][0] += a4.x * b4.x; acc[0][1] += a4.x * b4.y;
            acc[0][2] += a4.x * b4.z; acc[0][3] += a4.x * b4.w;
            acc[1][0] += a4.y * b4.x; acc[1][1] += a4.y * b4.y;
            acc[1][2] += a4.y * b4.z; acc[1][3] += a4.y * b4.w;
            acc[2][0] += a4.z * b4.x; acc[2][1] += a4.z * b4.y;
            acc[2][2] += a4.z * b4.z; acc[2][3] += a4.z * b4.w;
            acc[3][0] += a4.w * b4.x; acc[3][1] += a4.w * b4.y;
            acc[3][2] += a4.w * b4.z; acc[3][3] += a4.w * b4.w;
        }
    }
#pragma unroll
    for (int i = 0; i < 4; ++i) {
        int r = row0 + (ty << 2) + i;
        if (r < M) {
            float4 o = make_float4(acc[i][0], acc[i][1], acc[i][2], acc[i][3]);
            *(float4*)&C[(size_t)r * 256 + col0 + (tx << 2)] = o;
        }
    }
}

// ------------------------------------------- CSR aggregate (gather form)
// dst[c,:] = sum_{e in col==c} snorm[e]*h[srow[e],:] + dinv[c]^2*h[c,:] + bias
// One wave (64 lanes) per node; lane handles 4 consecutive floats (float4).
__global__ __launch_bounds__(256) void agg_kernel(const float* __restrict__ h,
                                                  const int* __restrict__ colptr,
                                                  const int* __restrict__ srow,
                                                  const float* __restrict__ snorm,
                                                  const float* __restrict__ dinv,
                                                  const float* __restrict__ bias,
                                                  float* __restrict__ dst, int n) {
    int wave = __builtin_amdgcn_readfirstlane(threadIdx.x >> 6);
    int lane = threadIdx.x & 63;
    int c = blockIdx.x * 4 + wave;
    if (c >= n) return;
    int p0 = colptr[c];
    int p1 = colptr[c + 1];
    float di = dinv[c];
    float self = di * di;

    const float4* h4 = (const float4*)h;
    int cbase = c * 64 + lane;

    float4 hv = h4[cbase];
    float ax = self * hv.x, ay = self * hv.y, az = self * hv.z, aw = self * hv.w;
    float bx = 0.f, by = 0.f, bz = 0.f, bw = 0.f;

    int j = p0;
    for (; j + 1 < p1; j += 2) {
        int r0 = srow[j];
        int r1 = srow[j + 1];
        float w0 = snorm[j];
        float w1 = snorm[j + 1];
        float4 v0 = h4[(size_t)r0 * 64 + lane];
        float4 v1 = h4[(size_t)r1 * 64 + lane];
        ax += w0 * v0.x; ay += w0 * v0.y; az += w0 * v0.z; aw += w0 * v0.w;
        bx += w1 * v1.x; by += w1 * v1.y; bz += w1 * v1.z; bw += w1 * v1.w;
    }
    if (j < p1) {
        int r0 = srow[j];
        float w0 = snorm[j];
        float4 v0 = h4[(size_t)r0 * 64 + lane];
        ax += w0 * v0.x; ay += w0 * v0.y; az += w0 * v0.z; aw += w0 * v0.w;
    }
    float4 bv = ((const float4*)bias)[lane];
    float4 o = make_float4(ax + bx + bv.x, ay + by + bv.y,
                           az + bz + bv.z, aw + bw + bv.w);
    ((float4*)dst)[cbase] = o;
}

// ----------------------------------------------------------------------
extern "C" void kernel_launch(void* const* d_in, const int* in_sizes, int n_in,
                              void* d_out, int out_size, void* d_ws, size_t ws_size,
                              hipStream_t stream) {
    const int*   node_features = (const int*)d_in[0];   // [T, N]
    const int*   edge_index    = (const int*)d_in[1];   // [T, 2, E]
    const float* edge_weight   = (const float*)d_in[2]; // [T, E]
    const float* emb           = (const float*)d_in[3]; // [VOCAB, D]
    const float* Wl[3] = {(const float*)d_in[4], (const float*)d_in[6], (const float*)d_in[8]};
    const float* bl[3] = {(const float*)d_in[5], (const float*)d_in[7], (const float*)d_in[9]};
    float* out = (float*)d_out;

    // workspace layout
    char* ws = (char*)d_ws;
    size_t off = 0;
    auto alloc = [&](size_t bytes) -> void* {
        void* p = ws + off;
        off = (off + bytes + 255) & ~(size_t)255;
        return p;
    };
    float* x      = (float*)alloc((size_t)NN * DD * 4);
    float* h      = (float*)alloc((size_t)NN * DD * 4);
    float* deg    = (float*)alloc((size_t)NN * 4);
    float* dinv   = (float*)alloc((size_t)NN * 4);
    int*   cnt    = (int*)alloc((size_t)NN * 4);
    int*   colptr = (int*)alloc((size_t)(NN + 1) * 4);
    int*   next   = (int*)alloc((size_t)NN * 4);
    int*   srow   = (int*)alloc((size_t)EE * 4);
    float* snorm  = (float*)alloc((size_t)EE * 4);
    (void)ws_size; (void)n_in; (void)in_sizes; (void)out_size;

    const int gN   = (NN + 255) / 256;
    const int gE   = (EE + 255) / 256;
    const int gX   = (NN * 64 + 255) / 256;
    const int gAgg = (NN + 3) / 4;
    dim3 gGemm(4, (NN + 63) / 64);

    for (int t = 0; t < T_STEPS; ++t) {
        const int*   ids = node_features + (size_t)t * NN;
        const int*   row = edge_index + (size_t)t * 2 * EE;
        const int*   col = row + EE;
        const float* w   = edge_weight + (size_t)t * EE;

        // per-timestep graph preprocessing (shared by all 3 layers)
        init_deg_cnt<<<gN, 256, 0, stream>>>(deg, cnt, NN);
        edge_deg_cnt<<<gE, 256, 0, stream>>>(col, w, deg, cnt, EE);
        compute_dinv<<<gN, 256, 0, stream>>>(deg, dinv, NN);
        scan_cnt<<<1, 1024, 0, stream>>>(cnt, colptr, next, NN);
        fill_csr<<<gE, 256, 0, stream>>>(row, col, w, dinv, next, srow, snorm, EE);

        // x = emb[ids]
        embed_kernel<<<gX, 256, 0, stream>>>(ids, emb, x, NN);

        for (int l = 0; l < 3; ++l) {
            sgemm_kernel<<<gGemm, 256, 0, stream>>>(x, Wl[l], h, NN);
            float* dst = (l == 2) ? (out + (size_t)t * NN * DD) : x;
            agg_kernel<<<gAgg, 256, 0, stream>>>(h, colptr, srow, snorm, dinv,
                                                 bl[l], dst, NN);
        }
    }
}

// Round 2
// 2972.211 us; speedup vs baseline: 1.2568x; 1.2568x over previous
//
#include <hip/hip_runtime.h>

// Problem constants (SpatialEncoding_46943992545790)
#define T_STEPS 4
#define NN 50000
#define EE 800000
#define DD 256
#define NB ((NN + 255) / 256)   // 196 scan blocks

// ---------------------------------------------------------------- bf16 helpers
__device__ __forceinline__ unsigned short f2bf(float f) {
    unsigned u = __float_as_uint(f);
    return (unsigned short)((u + 0x7FFFu + ((u >> 16) & 1u)) >> 16);  // RNE
}
__device__ __forceinline__ float bf2f(unsigned short s) {
    return __uint_as_float(((unsigned)s) << 16);
}

// ---------------------------------------------------------------- init
__global__ __launch_bounds__(256) void init_deg_cnt(float* __restrict__ deg,
                                                    int* __restrict__ cnt, int n) {
    int i = blockIdx.x * 256 + threadIdx.x;
    if (i < n) { deg[i] = 1.0f; cnt[i] = 0; }   // self-loop weight 1
}

// ------------------------------------------------- edge pass: deg + counts
__global__ __launch_bounds__(256) void edge_deg_cnt(const int* __restrict__ col,
                                                    const float* __restrict__ w,
                                                    float* __restrict__ deg,
                                                    int* __restrict__ cnt, int e) {
    int i = blockIdx.x * 256 + threadIdx.x;
    if (i < e) {
        int c = col[i];
        atomicAdd(&deg[c], w[i]);
        atomicAdd(&cnt[c], 1);
    }
}

// ---------------------------------------------------------------- dinv
__global__ __launch_bounds__(256) void compute_dinv(const float* __restrict__ deg,
                                                    float* __restrict__ dinv, int n) {
    int i = blockIdx.x * 256 + threadIdx.x;
    if (i < n) {
        float d = deg[i];
        dinv[i] = d > 0.0f ? rsqrtf(d) : 0.0f;
    }
}

// --------------------------------------------------- parallel scan, pass 1
__global__ __launch_bounds__(256) void block_sums(const int* __restrict__ cnt,
                                                  int* __restrict__ bsum, int n) {
    __shared__ int sm[256];
    int i = blockIdx.x * 256 + threadIdx.x;
    sm[threadIdx.x] = (i < n) ? cnt[i] : 0;
    __syncthreads();
    for (int s = 128; s > 0; s >>= 1) {
        if ((int)threadIdx.x < s) sm[threadIdx.x] += sm[threadIdx.x + s];
        __syncthreads();
    }
    if (threadIdx.x == 0) bsum[blockIdx.x] = sm[0];
}

// --------------------------------------------------- parallel scan, pass 2
__global__ __launch_bounds__(256) void scan_bsum(const int* __restrict__ bsum,
                                                 int* __restrict__ boff, int nb) {
    __shared__ int sm[256];
    int v = ((int)threadIdx.x < nb) ? bsum[threadIdx.x] : 0;
    sm[threadIdx.x] = v;
    __syncthreads();
    for (int o = 1; o < 256; o <<= 1) {
        int t = (threadIdx.x >= (unsigned)o) ? sm[threadIdx.x - o] : 0;
        __syncthreads();
        sm[threadIdx.x] += t;
        __syncthreads();
    }
    if ((int)threadIdx.x < nb) boff[threadIdx.x] = sm[threadIdx.x] - v;
}

// --------------------------------------------------- parallel scan, pass 3
__global__ __launch_bounds__(256) void scan_final(const int* __restrict__ cnt,
                                                  const int* __restrict__ boff,
                                                  int* __restrict__ colptr,
                                                  int* __restrict__ next, int n, int e) {
    __shared__ int sm[256];
    int i = blockIdx.x * 256 + threadIdx.x;
    int v = (i < n) ? cnt[i] : 0;
    sm[threadIdx.x] = v;
    __syncthreads();
    for (int o = 1; o < 256; o <<= 1) {
        int t = (threadIdx.x >= (unsigned)o) ? sm[threadIdx.x - o] : 0;
        __syncthreads();
        sm[threadIdx.x] += t;
        __syncthreads();
    }
    int excl = sm[threadIdx.x] - v + boff[blockIdx.x];
    if (i < n) { colptr[i] = excl; next[i] = excl; }
    if (i == 0) colptr[n] = e;   // every edge's col is in [0,n)
}

// --------------------------------------------- fill CSR (sorted by col)
__global__ __launch_bounds__(256) void fill_csr(const int* __restrict__ row,
                                                const int* __restrict__ col,
                                                const float* __restrict__ w,
                                                const float* __restrict__ dinv,
                                                int* __restrict__ next,
                                                int* __restrict__ srow,
                                                float* __restrict__ snorm, int e) {
    int i = blockIdx.x * 256 + threadIdx.x;
    if (i < e) {
        int r = row[i], c = col[i];
        int p = atomicAdd(&next[c], 1);
        srow[p] = r;
        snorm[p] = dinv[r] * w[i] * dinv[c];
    }
}

// ---------------------------------------------------- embedding gather
__global__ __launch_bounds__(256) void embed_kernel(const int* __restrict__ ids,
                                                    const float* __restrict__ emb,
                                                    float* __restrict__ x, int n) {
    int t = blockIdx.x * 256 + threadIdx.x;
    if (t < n * 64) {                   // 64 float4 per row (D=256)
        int node = t >> 6;
        int j = t & 63;
        ((float4*)x)[(size_t)node * 64 + j] =
            ((const float4*)emb)[(size_t)ids[node] * 64 + j];
    }
}

// ------------------------------------------------------- fp32 SGEMM -> bf16 out
// H2[M,256](bf16) = A[M,256] @ B[256,256], row-major.
// BM=128, BN=128, BK=16; 256 threads; 8x8 microtile per thread.
__global__ __launch_bounds__(256) void sgemm_kernel(const float* __restrict__ A,
                                                    const float* __restrict__ B,
                                                    unsigned short* __restrict__ H2,
                                                    int M) {
    __shared__ __align__(16) float As[16][132];   // [k][m], pad to break stride
    __shared__ __align__(16) float Bs[16][128];   // [k][n]

    int tid = threadIdx.x;
    int row0 = blockIdx.y * 128;
    int col0 = blockIdx.x * 128;
    int ty = tid >> 4, tx = tid & 15;     // 16x16 thread grid
    int m8 = ty << 3, n8 = tx << 3;       // 8x8 microtile origin

    // A-stage: m = tid/2 (0..127); two float4 at k = (tid&1)*4 and +8
    int am = tid >> 1, ak = (tid & 1) << 2;
    bool arow_ok = (row0 + am) < M;
    const float* Aptr = A + (size_t)(row0 + am) * 256 + ak;
    // B-stage: two float4; idx = tid*2+j -> k = idx>>5, n = (idx&31)*4
    int bidx0 = tid * 2;

    float acc[8][8];
#pragma unroll
    for (int i = 0; i < 8; ++i)
#pragma unroll
        for (int j = 0; j < 8; ++j) acc[i][j] = 0.0f;

    for (int k0 = 0; k0 < 256; k0 += 16) {
        float4 a0 = arow_ok ? *(const float4*)(Aptr + k0)
                            : make_float4(0.f, 0.f, 0.f, 0.f);
        float4 a1 = arow_ok ? *(const float4*)(Aptr + k0 + 8)
                            : make_float4(0.f, 0.f, 0.f, 0.f);
        int k_b0 = bidx0 >> 5,       n_b0 = (bidx0 & 31) << 2;
        int k_b1 = (bidx0 + 1) >> 5, n_b1 = ((bidx0 + 1) & 31) << 2;
        float4 b0 = *(const float4*)(B + (size_t)(k0 + k_b0) * 256 + col0 + n_b0);
        float4 b1 = *(const float4*)(B + (size_t)(k0 + k_b1) * 256 + col0 + n_b1);
        __syncthreads();
        As[ak + 0][am] = a0.x; As[ak + 1][am] = a0.y;
        As[ak + 2][am] = a0.z; As[ak + 3][am] = a0.w;
        As[ak + 8][am] = a1.x; As[ak + 9][am] = a1.y;
        As[ak + 10][am] = a1.z; As[ak + 11][am] = a1.w;
        *(float4*)&Bs[k_b0][n_b0] = b0;
        *(float4*)&Bs[k_b1][n_b1] = b1;
        __syncthreads();
#pragma unroll
        for (int k = 0; k < 16; ++k) {
            float4 aA = *(const float4*)&As[k][m8];
            float4 aB = *(const float4*)&As[k][m8 + 4];
            float4 bA = *(const float4*)&Bs[k][n8];
            float4 bB = *(const float4*)&Bs[k][n8 + 4];
            float av[8] = {aA.x, aA.y, aA.z, aA.w, aB.x, aB.y, aB.z, aB.w};
            float bv[8] = {bA.x, bA.y, bA.z, bA.w, bB.x, bB.y, bB.z, bB.w};
#pragma unroll
            for (int i = 0; i < 8; ++i)
#pragma unroll
                for (int j = 0; j < 8; ++j) acc[i][j] += av[i] * bv[j];
        }
    }
    // epilogue: convert 8 floats/row -> 8 bf16 (16 B store per row)
#pragma unroll
    for (int i = 0; i < 8; ++i) {
        int r = row0 + m8 + i;
        if (r < M) {
            uint4 o;
            o.x = (unsigned)f2bf(acc[i][0]) | ((unsigned)f2bf(acc[i][1]) << 16);
            o.y = (unsigned)f2bf(acc[i][2]) | ((unsigned)f2bf(acc[i][3]) << 16);
            o.z = (unsigned)f2bf(acc[i][4]) | ((unsigned)f2bf(acc[i][5]) << 16);
            o.w = (unsigned)f2bf(acc[i][6]) | ((unsigned)f2bf(acc[i][7]) << 16);
            *(uint4*)&H2[(size_t)r * 256 + col0 + n8] = o;
        }
    }
}

// ------------------------------------------- CSR aggregate (bf16 gather)
// dst[c,:] = sum_e snorm[e]*h2[srow[e],:] + dinv[c]^2*h2[c,:] + bias   (fp32 out)
// One wave per node; lane handles 4 consecutive cols (ushort4 = 8 B loads).
__global__ __launch_bounds__(256) void agg_kernel(const unsigned short* __restrict__ h2,
                                                  const int* __restrict__ colptr,
                                                  const int* __restrict__ srow,
                                                  const float* __restrict__ snorm,
                                                  const float* __restrict__ dinv,
                                                  const float* __restrict__ bias,
                                                  float* __restrict__ dst, int n) {
    int wave = threadIdx.x >> 6;
    int lane = threadIdx.x & 63;
    int c = blockIdx.x * 4 + wave;
    if (c >= n) return;
    int p0 = colptr[c];
    int p1 = colptr[c + 1];
    float di = dinv[c];
    float self = di * di;

    const ushort4* h4 = (const ushort4*)h2;   // 4 bf16 = 8 B per lane
    int cbase = c * 64 + lane;

    ushort4 sv = h4[cbase];
    float ax = self * bf2f(sv.x), ay = self * bf2f(sv.y);
    float az = self * bf2f(sv.z), aw = self * bf2f(sv.w);
    float bx = 0.f, by = 0.f, bz = 0.f, bw = 0.f;

    int j = p0;
    for (; j + 1 < p1; j += 2) {
        int r0 = srow[j];
        int r1 = srow[j + 1];
        float w0 = snorm[j];
        float w1 = snorm[j + 1];
        ushort4 v0 = h4[(size_t)r0 * 64 + lane];
        ushort4 v1 = h4[(size_t)r1 * 64 + lane];
        ax += w0 * bf2f(v0.x); ay += w0 * bf2f(v0.y);
        az += w0 * bf2f(v0.z); aw += w0 * bf2f(v0.w);
        bx += w1 * bf2f(v1.x); by += w1 * bf2f(v1.y);
        bz += w1 * bf2f(v1.z); bw += w1 * bf2f(v1.w);
    }
    if (j < p1) {
        int r0 = srow[j];
        float w0 = snorm[j];
        ushort4 v0 = h4[(size_t)r0 * 64 + lane];
        ax += w0 * bf2f(v0.x); ay += w0 * bf2f(v0.y);
        az += w0 * bf2f(v0.z); aw += w0 * bf2f(v0.w);
    }
    float4 bv = ((const float4*)bias)[lane];
    float4 o = make_float4(ax + bx + bv.x, ay + by + bv.y,
                           az + bz + bv.z, aw + bw + bv.w);
    ((float4*)dst)[cbase] = o;
}

// ----------------------------------------------------------------------
extern "C" void kernel_launch(void* const* d_in, const int* in_sizes, int n_in,
                              void* d_out, int out_size, void* d_ws, size_t ws_size,
                              hipStream_t stream) {
    const int*   node_features = (const int*)d_in[0];   // [T, N]
    const int*   edge_index    = (const int*)d_in[1];   // [T, 2, E]
    const float* edge_weight   = (const float*)d_in[2]; // [T, E]
    const float* emb           = (const float*)d_in[3]; // [VOCAB, D]
    const float* Wl[3] = {(const float*)d_in[4], (const float*)d_in[6], (const float*)d_in[8]};
    const float* bl[3] = {(const float*)d_in[5], (const float*)d_in[7], (const float*)d_in[9]};
    float* out = (float*)d_out;

    // workspace layout
    char* ws = (char*)d_ws;
    size_t off = 0;
    auto alloc = [&](size_t bytes) -> void* {
        void* p = ws + off;
        off = (off + bytes + 255) & ~(size_t)255;
        return p;
    };
    float*          x      = (float*)alloc((size_t)NN * DD * 4);
    unsigned short* h2     = (unsigned short*)alloc((size_t)NN * DD * 2);  // bf16
    float* deg    = (float*)alloc((size_t)NN * 4);
    float* dinv   = (float*)alloc((size_t)NN * 4);
    int*   cnt    = (int*)alloc((size_t)NN * 4);
    int*   colptr = (int*)alloc((size_t)(NN + 1) * 4);
    int*   next   = (int*)alloc((size_t)NN * 4);
    int*   srow   = (int*)alloc((size_t)EE * 4);
    float* snorm  = (float*)alloc((size_t)EE * 4);
    int*   bsum   = (int*)alloc((size_t)NB * 4);
    int*   boff   = (int*)alloc((size_t)NB * 4);
    (void)ws_size; (void)n_in; (void)in_sizes; (void)out_size;

    const int gN   = (NN + 255) / 256;   // == NB
    const int gE   = (EE + 255) / 256;
    const int gX   = (NN * 64 + 255) / 256;
    const int gAgg = (NN + 3) / 4;
    dim3 gGemm(2, (NN + 127) / 128);

    for (int t = 0; t < T_STEPS; ++t) {
        const int*   ids = node_features + (size_t)t * NN;
        const int*   row = edge_index + (size_t)t * 2 * EE;
        const int*   col = row + EE;
        const float* w   = edge_weight + (size_t)t * EE;

        // per-timestep graph preprocessing (shared by all 3 layers)
        init_deg_cnt<<<gN, 256, 0, stream>>>(deg, cnt, NN);
        edge_deg_cnt<<<gE, 256, 0, stream>>>(col, w, deg, cnt, EE);
        compute_dinv<<<gN, 256, 0, stream>>>(deg, dinv, NN);
        block_sums<<<NB, 256, 0, stream>>>(cnt, bsum, NN);
        scan_bsum<<<1, 256, 0, stream>>>(bsum, boff, NB);
        scan_final<<<NB, 256, 0, stream>>>(cnt, boff, colptr, next, NN, EE);
        fill_csr<<<gE, 256, 0, stream>>>(row, col, w, dinv, next, srow, snorm, EE);

        // x = emb[ids]
        embed_kernel<<<gX, 256, 0, stream>>>(ids, emb, x, NN);

        for (int l = 0; l < 3; ++l) {
            sgemm_kernel<<<gGemm, 256, 0, stream>>>(x, Wl[l], h2, NN);
            float* dst = (l == 2) ? (out + (size_t)t * NN * DD) : x;
            agg_kernel<<<gAgg, 256, 0, stream>>>(h2, colptr, srow, snorm, dinv,
                                                 bl[l], dst, NN);
        }
    }
}

// Round 3
// 1941.034 us; speedup vs baseline: 1.9244x; 1.5313x over previous
//
#include <hip/hip_runtime.h>

// Problem constants (SpatialEncoding_46943992545790)
#define T_STEPS 4
#define NN 50000
#define EE 800000
#define DD 256
#define NB ((NN + 255) / 256)   // 196 scan blocks

typedef __attribute__((ext_vector_type(8))) short short8;
typedef __attribute__((ext_vector_type(4))) float floatx4;

// ---------------------------------------------------------------- bf16 helpers
__device__ __forceinline__ unsigned short f2bf(float f) {
    unsigned u = __float_as_uint(f);
    return (unsigned short)((u + 0x7FFFu + ((u >> 16) & 1u)) >> 16);  // RNE
}
__device__ __forceinline__ float bf2f(unsigned short s) {
    return __uint_as_float(((unsigned)s) << 16);
}

__device__ __forceinline__ void async16(const unsigned short* g, unsigned short* l) {
    __builtin_amdgcn_global_load_lds(
        (const __attribute__((address_space(1))) void*)g,
        (__attribute__((address_space(3))) void*)l, 16, 0, 0);
}

// ---------------------------------------------------------------- init
__global__ __launch_bounds__(256) void init_deg_cnt(float* __restrict__ deg,
                                                    int* __restrict__ cnt, int n) {
    int i = blockIdx.x * 256 + threadIdx.x;
    if (i < n) { deg[i] = 1.0f; cnt[i] = 0; }   // self-loop weight 1
}

// ------------------------------------------------- edge pass: deg + counts
__global__ __launch_bounds__(256) void edge_deg_cnt(const int* __restrict__ col,
                                                    const float* __restrict__ w,
                                                    float* __restrict__ deg,
                                                    int* __restrict__ cnt, int e) {
    int i = blockIdx.x * 256 + threadIdx.x;
    if (i < e) {
        int c = col[i];
        atomicAdd(&deg[c], w[i]);
        atomicAdd(&cnt[c], 1);
    }
}

// ---------------------------------------------------------------- dinv
__global__ __launch_bounds__(256) void compute_dinv(const float* __restrict__ deg,
                                                    float* __restrict__ dinv, int n) {
    int i = blockIdx.x * 256 + threadIdx.x;
    if (i < n) {
        float d = deg[i];
        dinv[i] = d > 0.0f ? rsqrtf(d) : 0.0f;
    }
}

// --------------------------------------------------- parallel scan, pass 1
__global__ __launch_bounds__(256) void block_sums(const int* __restrict__ cnt,
                                                  int* __restrict__ bsum, int n) {
    __shared__ int sm[256];
    int i = blockIdx.x * 256 + threadIdx.x;
    sm[threadIdx.x] = (i < n) ? cnt[i] : 0;
    __syncthreads();
    for (int s = 128; s > 0; s >>= 1) {
        if ((int)threadIdx.x < s) sm[threadIdx.x] += sm[threadIdx.x + s];
        __syncthreads();
    }
    if (threadIdx.x == 0) bsum[blockIdx.x] = sm[0];
}

// --------------------------------------------------- parallel scan, pass 2
__global__ __launch_bounds__(256) void scan_bsum(const int* __restrict__ bsum,
                                                 int* __restrict__ boff, int nb) {
    __shared__ int sm[256];
    int v = ((int)threadIdx.x < nb) ? bsum[threadIdx.x] : 0;
    sm[threadIdx.x] = v;
    __syncthreads();
    for (int o = 1; o < 256; o <<= 1) {
        int t = (threadIdx.x >= (unsigned)o) ? sm[threadIdx.x - o] : 0;
        __syncthreads();
        sm[threadIdx.x] += t;
        __syncthreads();
    }
    if ((int)threadIdx.x < nb) boff[threadIdx.x] = sm[threadIdx.x] - v;
}

// --------------------------------------------------- parallel scan, pass 3
__global__ __launch_bounds__(256) void scan_final(const int* __restrict__ cnt,
                                                  const int* __restrict__ boff,
                                                  int* __restrict__ colptr,
                                                  int* __restrict__ next, int n, int e) {
    __shared__ int sm[256];
    int i = blockIdx.x * 256 + threadIdx.x;
    int v = (i < n) ? cnt[i] : 0;
    sm[threadIdx.x] = v;
    __syncthreads();
    for (int o = 1; o < 256; o <<= 1) {
        int t = (threadIdx.x >= (unsigned)o) ? sm[threadIdx.x - o] : 0;
        __syncthreads();
        sm[threadIdx.x] += t;
        __syncthreads();
    }
    int excl = sm[threadIdx.x] - v + boff[blockIdx.x];
    if (i < n) { colptr[i] = excl; next[i] = excl; }
    if (i == 0) colptr[n] = e;   // every edge's col is in [0,n)
}

// --------------------------------------------- fill CSR (sorted by col)
__global__ __launch_bounds__(256) void fill_csr(const int* __restrict__ row,
                                                const int* __restrict__ col,
                                                const float* __restrict__ w,
                                                const float* __restrict__ dinv,
                                                int* __restrict__ next,
                                                int* __restrict__ srow,
                                                float* __restrict__ snorm, int e) {
    int i = blockIdx.x * 256 + threadIdx.x;
    if (i < e) {
        int r = row[i], c = col[i];
        int p = atomicAdd(&next[c], 1);
        srow[p] = r;
        snorm[p] = dinv[r] * w[i] * dinv[c];
    }
}

// --------------------------------- convert W[k][n] fp32 -> Wt[n][k] bf16 (x3)
__global__ __launch_bounds__(256) void convert_w(const float* __restrict__ W0,
                                                 const float* __restrict__ W1,
                                                 const float* __restrict__ W2,
                                                 unsigned short* __restrict__ wt) {
    int n = blockIdx.x;          // 0..255
    int k = threadIdx.x;         // 0..255
    int l = blockIdx.y;          // layer 0..2
    const float* W = (l == 0) ? W0 : (l == 1) ? W1 : W2;
    wt[(size_t)l * 65536 + n * 256 + k] = f2bf(W[k * 256 + n]);
}

// ---------------------------------------------------- embedding gather -> bf16
__global__ __launch_bounds__(256) void embed_kernel(const int* __restrict__ ids,
                                                    const float* __restrict__ emb,
                                                    unsigned short* __restrict__ xb,
                                                    int n) {
    int t = blockIdx.x * 256 + threadIdx.x;
    if (t < n * 64) {                   // 64 float4 per row (D=256)
        int node = t >> 6;
        int j = t & 63;
        float4 v = ((const float4*)emb)[(size_t)ids[node] * 64 + j];
        ushort4 o;
        o.x = f2bf(v.x); o.y = f2bf(v.y); o.z = f2bf(v.z); o.w = f2bf(v.w);
        ((ushort4*)xb)[(size_t)node * 64 + j] = o;
    }
}

// ------------------------------------------------------- bf16 MFMA GEMM
// h2[M,256](bf16) = xb[M,256](bf16) @ W, with wt = W^T (bf16, [n][k] row-major).
// BM=128, BN=128, BK=32. 256 threads = 4 waves; wave computes 64x64 via
// 4x4 grid of 16x16x32 MFMA tiles. LDS: chunk-column-major (chunk = 8 bf16):
// As[c*128 + m] holds A[row0+m][k0 + c*8 .. +7]; same for Bs with n.
__global__ __launch_bounds__(256) void mfma_gemm(const unsigned short* __restrict__ xb,
                                                 const unsigned short* __restrict__ wt,
                                                 unsigned short* __restrict__ h2,
                                                 int M) {
    __shared__ __align__(16) unsigned short As[128 * 32];
    __shared__ __align__(16) unsigned short Bs[128 * 32];

    int tid = threadIdx.x;
    int lane = tid & 63;
    int wave = tid >> 6;
    int row0 = blockIdx.y * 128;
    int col0 = blockIdx.x * 128;
    int wm = (wave & 1) * 64;
    int wn = (wave >> 1) * 64;
    int quad = lane >> 4;
    int cl = lane & 15;

    // staging decomposition (constant across K-iters): idx = s*256 + tid
    int idx0 = tid, idx1 = 256 + tid;
    int c0 = idx0 >> 7, m0 = idx0 & 127;
    int c1 = idx1 >> 7, m1 = idx1 & 127;
    int gr0 = row0 + m0; if (gr0 >= M) gr0 = M - 1;
    int gr1 = row0 + m1; if (gr1 >= M) gr1 = M - 1;
    const unsigned short* srcA0 = xb + (size_t)gr0 * 256 + c0 * 8;
    const unsigned short* srcA1 = xb + (size_t)gr1 * 256 + c1 * 8;
    const unsigned short* srcB0 = wt + (size_t)(col0 + m0) * 256 + c0 * 8;
    const unsigned short* srcB1 = wt + (size_t)(col0 + m1) * 256 + c1 * 8;
    unsigned short* dstA0 = As + idx0 * 8;
    unsigned short* dstA1 = As + idx1 * 8;
    unsigned short* dstB0 = Bs + idx0 * 8;
    unsigned short* dstB1 = Bs + idx1 * 8;

    floatx4 acc[4][4] = {};

    for (int k0 = 0; k0 < 256; k0 += 32) {
        if (k0) __syncthreads();          // protect LDS from prior reads
        async16(srcA0 + k0, dstA0);
        async16(srcA1 + k0, dstA1);
        async16(srcB0 + k0, dstB0);
        async16(srcB1 + k0, dstB1);
        __syncthreads();                  // drains vmcnt before barrier

        short8 af[4], bfr[4];
#pragma unroll
        for (int i = 0; i < 4; ++i)
            af[i] = *(const short8*)&As[(quad * 128 + wm + i * 16 + cl) * 8];
#pragma unroll
        for (int j = 0; j < 4; ++j)
            bfr[j] = *(const short8*)&Bs[(quad * 128 + wn + j * 16 + cl) * 8];
#pragma unroll
        for (int i = 0; i < 4; ++i)
#pragma unroll
            for (int j = 0; j < 4; ++j)
                acc[i][j] = __builtin_amdgcn_mfma_f32_16x16x32_bf16(
                    af[i], bfr[j], acc[i][j], 0, 0, 0);
    }

    // epilogue: D[row=quad*4+reg][col=lane&15] per 16x16 tile
#pragma unroll
    for (int i = 0; i < 4; ++i) {
#pragma unroll
        for (int r = 0; r < 4; ++r) {
            int gr = row0 + wm + i * 16 + quad * 4 + r;
            if (gr < M) {
                size_t base = (size_t)gr * 256 + col0 + wn + cl;
#pragma unroll
                for (int j = 0; j < 4; ++j)
                    h2[base + j * 16] = f2bf(acc[i][j][r]);
            }
        }
    }
}

// ------------------------------------------- CSR aggregate (bf16 gather)
// dst[c,:] = sum_e snorm[e]*h2[srow[e],:] + dinv[c]^2*h2[c,:] + bias
// fp32 accumulate; writes bf16 (intermediate) or fp32 (final output).
__global__ __launch_bounds__(256) void agg_kernel(const unsigned short* __restrict__ h2,
                                                  const int* __restrict__ colptr,
                                                  const int* __restrict__ srow,
                                                  const float* __restrict__ snorm,
                                                  const float* __restrict__ dinv,
                                                  const float* __restrict__ bias,
                                                  float* __restrict__ dstf,
                                                  unsigned short* __restrict__ dstb,
                                                  int n) {
    int wave = threadIdx.x >> 6;
    int lane = threadIdx.x & 63;
    int c = blockIdx.x * 4 + wave;
    if (c >= n) return;
    int p0 = colptr[c];
    int p1 = colptr[c + 1];
    float di = dinv[c];
    float self = di * di;

    const ushort4* h4 = (const ushort4*)h2;   // 4 bf16 = 8 B per lane
    int cbase = c * 64 + lane;

    ushort4 sv = h4[cbase];
    float ax = self * bf2f(sv.x), ay = self * bf2f(sv.y);
    float az = self * bf2f(sv.z), aw = self * bf2f(sv.w);
    float bx = 0.f, by = 0.f, bz = 0.f, bw = 0.f;

    int j = p0;
    for (; j + 1 < p1; j += 2) {
        int r0 = srow[j];
        int r1 = srow[j + 1];
        float w0 = snorm[j];
        float w1 = snorm[j + 1];
        ushort4 v0 = h4[(size_t)r0 * 64 + lane];
        ushort4 v1 = h4[(size_t)r1 * 64 + lane];
        ax += w0 * bf2f(v0.x); ay += w0 * bf2f(v0.y);
        az += w0 * bf2f(v0.z); aw += w0 * bf2f(v0.w);
        bx += w1 * bf2f(v1.x); by += w1 * bf2f(v1.y);
        bz += w1 * bf2f(v1.z); bw += w1 * bf2f(v1.w);
    }
    if (j < p1) {
        int r0 = srow[j];
        float w0 = snorm[j];
        ushort4 v0 = h4[(size_t)r0 * 64 + lane];
        ax += w0 * bf2f(v0.x); ay += w0 * bf2f(v0.y);
        az += w0 * bf2f(v0.z); aw += w0 * bf2f(v0.w);
    }
    float4 bv = ((const float4*)bias)[lane];
    float ox = ax + bx + bv.x, oy = ay + by + bv.y;
    float oz = az + bz + bv.z, ow = aw + bw + bv.w;
    if (dstb) {
        ushort4 o;
        o.x = f2bf(ox); o.y = f2bf(oy); o.z = f2bf(oz); o.w = f2bf(ow);
        ((ushort4*)dstb)[cbase] = o;
    } else {
        ((float4*)dstf)[cbase] = make_float4(ox, oy, oz, ow);
    }
}

// ----------------------------------------------------------------------
extern "C" void kernel_launch(void* const* d_in, const int* in_sizes, int n_in,
                              void* d_out, int out_size, void* d_ws, size_t ws_size,
                              hipStream_t stream) {
    const int*   node_features = (const int*)d_in[0];   // [T, N]
    const int*   edge_index    = (const int*)d_in[1];   // [T, 2, E]
    const float* edge_weight   = (const float*)d_in[2]; // [T, E]
    const float* emb           = (const float*)d_in[3]; // [VOCAB, D]
    const float* Wl[3] = {(const float*)d_in[4], (const float*)d_in[6], (const float*)d_in[8]};
    const float* bl[3] = {(const float*)d_in[5], (const float*)d_in[7], (const float*)d_in[9]};
    float* out = (float*)d_out;

    // workspace layout
    char* ws = (char*)d_ws;
    size_t off = 0;
    auto alloc = [&](size_t bytes) -> void* {
        void* p = ws + off;
        off = (off + bytes + 255) & ~(size_t)255;
        return p;
    };
    unsigned short* xb     = (unsigned short*)alloc((size_t)NN * DD * 2);  // bf16
    unsigned short* h2     = (unsigned short*)alloc((size_t)NN * DD * 2);  // bf16
    unsigned short* wt     = (unsigned short*)alloc((size_t)3 * DD * DD * 2);
    float* deg    = (float*)alloc((size_t)NN * 4);
    float* dinv   = (float*)alloc((size_t)NN * 4);
    int*   cnt    = (int*)alloc((size_t)NN * 4);
    int*   colptr = (int*)alloc((size_t)(NN + 1) * 4);
    int*   next   = (int*)alloc((size_t)NN * 4);
    int*   srow   = (int*)alloc((size_t)EE * 4);
    float* snorm  = (float*)alloc((size_t)EE * 4);
    int*   bsum   = (int*)alloc((size_t)NB * 4);
    int*   boff   = (int*)alloc((size_t)NB * 4);
    (void)ws_size; (void)n_in; (void)in_sizes; (void)out_size;

    const int gN   = (NN + 255) / 256;   // == NB
    const int gE   = (EE + 255) / 256;
    const int gX   = (NN * 64 + 255) / 256;
    const int gAgg = (NN + 3) / 4;
    dim3 gGemm(2, (NN + 127) / 128);
    dim3 gCvt(256, 3);

    // weights -> bf16 transposed, once per launch
    convert_w<<<gCvt, 256, 0, stream>>>(Wl[0], Wl[1], Wl[2], wt);

    for (int t = 0; t < T_STEPS; ++t) {
        const int*   ids = node_features + (size_t)t * NN;
        const int*   row = edge_index + (size_t)t * 2 * EE;
        const int*   col = row + EE;
        const float* w   = edge_weight + (size_t)t * EE;

        // per-timestep graph preprocessing (shared by all 3 layers)
        init_deg_cnt<<<gN, 256, 0, stream>>>(deg, cnt, NN);
        edge_deg_cnt<<<gE, 256, 0, stream>>>(col, w, deg, cnt, EE);
        compute_dinv<<<gN, 256, 0, stream>>>(deg, dinv, NN);
        block_sums<<<NB, 256, 0, stream>>>(cnt, bsum, NN);
        scan_bsum<<<1, 256, 0, stream>>>(bsum, boff, NB);
        scan_final<<<NB, 256, 0, stream>>>(cnt, boff, colptr, next, NN, EE);
        fill_csr<<<gE, 256, 0, stream>>>(row, col, w, dinv, next, srow, snorm, EE);

        // x = emb[ids]  (bf16)
        embed_kernel<<<gX, 256, 0, stream>>>(ids, emb, xb, NN);

        for (int l = 0; l < 3; ++l) {
            mfma_gemm<<<gGemm, 256, 0, stream>>>(xb, wt + (size_t)l * DD * DD, h2, NN);
            if (l == 2) {
                agg_kernel<<<gAgg, 256, 0, stream>>>(h2, colptr, srow, snorm, dinv,
                                                     bl[l], out + (size_t)t * NN * DD,
                                                     nullptr, NN);
            } else {
                agg_kernel<<<gAgg, 256, 0, stream>>>(h2, colptr, srow, snorm, dinv,
                                                     bl[l], nullptr, xb, NN);
            }
        }
    }
}